// Round 2
// baseline (594.162 us; speedup 1.0000x reference)
//
#include <hip/hip_runtime.h>

#define NSTEPS 128
#define MIN_NEAR 0.2f
#define T_THRESH 1e-4f

// one wave (64 lanes) per ray; lane i handles steps 2i and 2i+1.
// Inputs/outputs are float32 per the reference (jax default dtype).
__global__ __launch_bounds__(256) void nerf_composite(
    const float* __restrict__ rays_o,
    const float* __restrict__ rays_d,
    const float* __restrict__ sigmas,
    const float* __restrict__ rgbs,
    float* __restrict__ out,   // [3N image | N depth | N depth_norm]
    int N)
{
    const int ray  = blockIdx.x * 4 + (threadIdx.x >> 6);
    const int lane = threadIdx.x & 63;
    if (ray >= N) return;

    // ---- ray origin / direction (wave-uniform scalar loads) ----
    const float o0 = rays_o[3 * ray + 0];
    const float o1 = rays_o[3 * ray + 1];
    const float o2 = rays_o[3 * ray + 2];
    const float d0 = rays_d[3 * ray + 0];
    const float d1 = rays_d[3 * ray + 1];
    const float d2 = rays_d[3 * ray + 2];

    // ---- slab test against [-1, 1]^3 (matches reference exactly) ----
    float tmin = -3.0e38f, tmax = 3.0e38f;
    {
        float dc, ta, tb;
        dc = (fabsf(d0) < 1e-8f) ? 1e-8f : d0;
        ta = (-1.0f - o0) / dc;  tb = (1.0f - o0) / dc;
        tmin = fmaxf(tmin, fminf(ta, tb));  tmax = fminf(tmax, fmaxf(ta, tb));
        dc = (fabsf(d1) < 1e-8f) ? 1e-8f : d1;
        ta = (-1.0f - o1) / dc;  tb = (1.0f - o1) / dc;
        tmin = fmaxf(tmin, fminf(ta, tb));  tmax = fminf(tmax, fmaxf(ta, tb));
        dc = (fabsf(d2) < 1e-8f) ? 1e-8f : d2;
        ta = (-1.0f - o2) / dc;  tb = (1.0f - o2) / dc;
        tmin = fmaxf(tmin, fminf(ta, tb));  tmax = fminf(tmax, fmaxf(ta, tb));
    }
    const float nearv = fmaxf(tmin, MIN_NEAR);
    const float farv  = fmaxf(tmax, nearv + 1e-4f);
    const float delta = (farv - nearv) * (1.0f / (float)NSTEPS);

    // ---- coalesced vector loads: 2 sigmas (8B) + 2 rgb triplets (24B)/lane ----
    const float2* sp = (const float2*)(sigmas + (size_t)ray * NSTEPS);
    const float2 sv = sp[lane];                      // steps 2*lane, 2*lane+1
    const float2* rp = (const float2*)(rgbs + (size_t)ray * NSTEPS * 3);
    const float2 c0 = rp[3 * lane + 0];              // r0 g0
    const float2 c1 = rp[3 * lane + 1];              // b0 r1
    const float2 c2 = rp[3 * lane + 2];              // g1 b1

    const float s0 = sv.x, s1 = sv.y;
    const float r0 = c0.x, g0 = c0.y, b0 = c1.x;
    const float r1 = c1.y, g1 = c2.x, b1 = c2.y;

    // alphas and survival factors (reference: f = 1 - alpha + 1e-10)
    const float e0 = __expf(-s0 * delta);
    const float e1 = __expf(-s1 * delta);
    const float a0 = 1.0f - e0;
    const float a1 = 1.0f - e1;
    const float f0 = e0 + 1e-10f;
    const float f1 = e1 + 1e-10f;

    // ---- exclusive transmittance via wave product-scan of p = f0*f1 ----
    float scan = f0 * f1;
    #pragma unroll
    for (int off = 1; off < 64; off <<= 1) {
        float v = __shfl_up(scan, off, 64);
        if (lane >= off) scan *= v;
    }
    float Texc = __shfl_up(scan, 1, 64);  // exclusive across lanes
    if (lane == 0) Texc = 1.0f;
    const float T0 = Texc;        // T before step 2*lane
    const float T1 = Texc * f0;   // T before step 2*lane+1

    const float w0 = (T0 > T_THRESH) ? a0 * T0 : 0.0f;
    const float w1 = (T1 > T_THRESH) ? a1 * T1 : 0.0f;

    const float t0 = nearv + ((float)(2 * lane) + 0.5f) * delta;
    const float t1 = nearv + ((float)(2 * lane) + 1.5f) * delta;

    float ws = w0 + w1;
    float dp = w0 * t0 + w1 * t1;
    float ir = w0 * r0 + w1 * r1;
    float ig = w0 * g0 + w1 * g1;
    float ib = w0 * b0 + w1 * b1;

    // ---- butterfly reduce 5 accumulators across the wave ----
    #pragma unroll
    for (int off = 32; off > 0; off >>= 1) {
        ws += __shfl_xor(ws, off, 64);
        dp += __shfl_xor(dp, off, 64);
        ir += __shfl_xor(ir, off, 64);
        ig += __shfl_xor(ig, off, 64);
        ib += __shfl_xor(ib, off, 64);
    }

    if (lane == 0) {
        const float bg = 1.0f - ws;   // BG_COLOR = 1.0
        out[3 * ray + 0] = ir + bg;
        out[3 * ray + 1] = ig + bg;
        out[3 * ray + 2] = ib + bg;
        out[3 * N + ray] = dp;
        out[4 * N + ray] = fmaxf(dp - nearv, 0.0f) / (farv - nearv);
    }
}

extern "C" void kernel_launch(void* const* d_in, const int* in_sizes, int n_in,
                              void* d_out, int out_size, void* d_ws, size_t ws_size,
                              hipStream_t stream) {
    const float* rays_o = (const float*)d_in[0];
    const float* rays_d = (const float*)d_in[1];
    const float* sigmas = (const float*)d_in[2];
    const float* rgbs   = (const float*)d_in[3];
    float* out = (float*)d_out;

    const int N = in_sizes[0] / 3;           // 262144 rays
    const int raysPerBlock = 4;              // 256 threads = 4 waves
    const int grid = (N + raysPerBlock - 1) / raysPerBlock;
    nerf_composite<<<grid, 256, 0, stream>>>(rays_o, rays_d, sigmas, rgbs, out, N);
}